// Round 1
// 664.757 us; speedup vs baseline: 1.0087x; 1.0087x over previous
//
#include <hip/hip_runtime.h>
#include <math.h>

#define L_DIM 4096
#define B_DIM 32
#define H_DIM 1024

// Kernel 0: transpose hidden (H,B) -> hT (B,H) so energy blocks can stage
// their hidden column with coalesced float4 reads instead of 128B-strided ones.
__global__ void transpose_hidden_k(const float* __restrict__ hidden,
                                   float* __restrict__ hT) {
    int tid = blockIdx.x * blockDim.x + threadIdx.x; // tid = h*B + b
    int h = tid / B_DIM;
    int b = tid % B_DIM;
    hT[b * H_DIM + h] = hidden[tid];
}

// Kernel 1: energies[b][l] = dot(hT[b][:], enc[l][b][:])
// One wave (64 lanes) per (l, b) pair. 4 waves per block share one b.
//
// CRITICAL mapping choice: b varies FASTEST across blockIdx. With b slowest
// (previous version), the ~2048 concurrently-resident blocks all shared 1-2 b
// values, so the resident set read only 4-8 KB out of every 128 KB stride of
// enc -> power-of-2 aliasing onto a small subset of HBM channels (~1.6 TB/s).
// With b fastest, 32 consecutive blocks (one l-group, all b) read a fully
// contiguous 512 KB stripe -> uniform channel coverage, streaming BW.
__global__ __launch_bounds__(256) void energies_k(const float* __restrict__ hT,
                                                  const float* __restrict__ enc,
                                                  float* __restrict__ out) {
    __shared__ float sh[H_DIM];
    const int bid = blockIdx.x;
    const int b  = bid & 31;         // b fastest
    const int lg = bid >> 5;         // l-group of 4
    const int t  = threadIdx.x;

    // stage hidden row b into LDS: 256 threads x float4 = 1024 floats (4 KB)
    ((float4*)sh)[t] = ((const float4*)(hT + b * H_DIM))[t];
    __syncthreads();

    const int wave = t >> 6;
    const int lane = t & 63;
    const int l = lg * 4 + wave;

    const float4* ep = (const float4*)(enc + (size_t)l * (B_DIM * H_DIM) + (size_t)b * H_DIM);
    const float4* sp = (const float4*)sh;

    float acc = 0.f;
#pragma unroll
    for (int k = 0; k < 4; ++k) {
        float4 e = ep[k * 64 + lane];
        float4 h = sp[k * 64 + lane];
        acc += e.x * h.x + e.y * h.y + e.z * h.z + e.w * h.w;
    }
#pragma unroll
    for (int off = 32; off > 0; off >>= 1)
        acc += __shfl_down(acc, off, 64);

    if (lane == 0) out[b * L_DIM + l] = acc;
}

// Kernel 2: in-place softmax over L for each b. One block per b.
__global__ __launch_bounds__(256) void softmax_k(float* __restrict__ out) {
    __shared__ float red[4];
    const int b = blockIdx.x;
    float* row = out + b * L_DIM;
    const int t = threadIdx.x;
    const int lane = t & 63;
    const int wave = t >> 6;

    float vals[16];
    float m = -INFINITY;
#pragma unroll
    for (int k = 0; k < 16; ++k) {
        vals[k] = row[t + k * 256];
        m = fmaxf(m, vals[k]);
    }
#pragma unroll
    for (int off = 32; off > 0; off >>= 1)
        m = fmaxf(m, __shfl_down(m, off, 64));
    if (lane == 0) red[wave] = m;
    __syncthreads();
    m = fmaxf(fmaxf(red[0], red[1]), fmaxf(red[2], red[3]));
    __syncthreads();

    float s = 0.f;
#pragma unroll
    for (int k = 0; k < 16; ++k) {
        vals[k] = expf(vals[k] - m);
        s += vals[k];
    }
#pragma unroll
    for (int off = 32; off > 0; off >>= 1)
        s += __shfl_down(s, off, 64);
    if (lane == 0) red[wave] = s;
    __syncthreads();
    s = red[0] + red[1] + red[2] + red[3];

    const float inv = 1.0f / s;
#pragma unroll
    for (int k = 0; k < 16; ++k)
        row[t + k * 256] = vals[k] * inv;
}

extern "C" void kernel_launch(void* const* d_in, const int* in_sizes, int n_in,
                              void* d_out, int out_size, void* d_ws, size_t ws_size,
                              hipStream_t stream) {
    const float* hidden = (const float*)d_in[0];   // (H, B)
    const float* enc    = (const float*)d_in[1];   // (L, B, H)
    float* out = (float*)d_out;                    // (B, 1, L) flat = b*L + l
    float* hT  = (float*)d_ws;                     // (B, H) scratch, 128 KB

    transpose_hidden_k<<<(H_DIM * B_DIM) / 256, 256, 0, stream>>>(hidden, hT);
    energies_k<<<B_DIM * (L_DIM / 4), 256, 0, stream>>>(hT, enc, out);
    softmax_k<<<B_DIM, 256, 0, stream>>>(out);
}